// Round 10
// baseline (129.819 us; speedup 1.0000x reference)
//
#include <hip/hip_runtime.h>

// BLAMem: truncated tensor-algebra (depth 4, C=8) log-signature memory.
// Round-17: R9's fused mega-kernel (fold+scan+apply+gemv+final, flag dataflow,
// ~30MB coalesced uncached traffic) widened to 512-THREAD BLOCKS.
// R9 post-mortem: correct, 89us, VALUBusy 9% -- at 256 blocks x 256 threads and
// 111KB LDS the machine runs 1 wave/SIMD: every LDS chain, uncached load and poll
// is latency-exposed. 512 threads/block = 8 waves = 2/SIMD doubles latency hiding
// in the dominant fold/apply phases. Math: each thread now owns ONE L4 row (the
// old a/b dual split across threads) -- per-element FP sequences bit-identical.
// Scan/gemv/final keep their verified 256-thread bodies under tid<256 guards with
// barriers hoisted to top level. Sync: R7/R9-validated fence-free sc0sc1 flags,
// ~40ms timeouts (bug => wrong answer, never a hang). NO atomic RMW anywhere.

#define MEM   4680   // 8 + 64 + 512 + 4096 (unpadded global layout)
#define NG    32     // groups per batch
#define TLEN  2048

#define P3OFF 72
#define P4OFF 648
#define SIGSZ 5256

__device__ __forceinline__ float ldc(const float* p) {
    return __hip_atomic_load(p, __ATOMIC_RELAXED, __HIP_MEMORY_SCOPE_SYSTEM);
}
__device__ __forceinline__ void stc(float* p, float v) {
    __hip_atomic_store(p, v, __ATOMIC_RELAXED, __HIP_MEMORY_SCOPE_SYSTEM);
}
__device__ __forceinline__ unsigned ldu(const unsigned* p) {
    return __hip_atomic_load(p, __ATOMIC_RELAXED, __HIP_MEMORY_SCOPE_SYSTEM);
}
__device__ __forceinline__ void stu(unsigned* p, unsigned v) {
    __hip_atomic_store(p, v, __ATOMIC_RELAXED, __HIP_MEMORY_SCOPE_SYSTEM);
}
#define SPIN_TIMEOUT 4000000ull   // ~40ms

__device__ __forceinline__ void waitflag(const unsigned* f) {
    unsigned long long t0 = __builtin_amdgcn_s_memrealtime();
    while (ldu(f) == 0u) {
        __builtin_amdgcn_s_sleep(2);
        if (__builtin_amdgcn_s_memrealtime() - t0 > SPIN_TIMEOUT) break;
    }
}

// smem layout (floats): sSnap [0,21024) persistent through apply.
// Aliased @21024: fold {sInc 512, U 648}; scan {6656}; apply {sR 648, sG 4096};
// gemv {sp 256}; final {sRed 256}. Total 27680 floats = 110.7KB -> 1 block/CU.
#define SMEM_TOTAL 27680

__global__ __launch_bounds__(512) void mega_kernel(
    const float* __restrict__ x,  const float* __restrict__ W1,
    const float* __restrict__ b1, const float* __restrict__ W2,
    const float* __restrict__ b2, float* __restrict__ outp,
    float* __restrict__ T, float* __restrict__ P,
    float* __restrict__ partial, float* __restrict__ hpart,
    unsigned* __restrict__ flags)
{
    const int bid = blockIdx.x;
    const int tid = threadIdx.x;          // 0..511 : one L4 row per thread
    const int b = bid >> 5, g = bid & 31;

    __shared__ __attribute__((aligned(16))) float smem[SMEM_TOTAL];

    unsigned* fflag = flags;          // 256 fold-done
    unsigned* sflag = flags + 256;    // 128 scan-done
    unsigned* aflag = flags + 384;    // 256 apply-done
    unsigned* gflag = flags + 640;    // 147 gemv-done

    float* sSnap0 = smem;             // 4 x SIGSZ

    const int i1 = tid >> 6;          // i   of row (i,j,k)
    const int j1 = (tid >> 3) & 7;    // j
    const int k1 = tid & 7;           // k
    const int row1 = tid >> 3;        // ij in [0,64)
    const int jk = tid & 63;          // jk in [0,64)

    // ================= phase 1: fold (all 256 blocks), snapshots in LDS ========
    {
        float* sInc = smem + 21024;    // 512
        float* U    = smem + 21536;    // 648
        float* loc3 = U;               // 576 (64 rows x 9)
        float* loc2 = U + 576;         // 64
        float* loc1 = U + 640;         // 8

        {   // one element per thread
            int e = tid;
            int s = e >> 3, c = e & 7;
            int t = g * 64 + s;
            float v;
            if (c < 7) {
                float cur  = x[(b * TLEN + t) * 7 + c];
                float prev = (t > 0) ? x[(b * TLEN + t - 1) * 7 + c] : 0.f;
                v = cur - prev;
            } else v = (t > 0) ? (1.f / 2047.f) : 0.f;
            sInc[e] = v;
        }
        __syncthreads();

        for (int c = 0; c < 4; ++c) {
            const float* dch = &sInc[c * 128];
            float p1 = 0.f, l2 = 0.f, l3 = 0.f;
            float S4[8];
#pragma unroll
            for (int l = 0; l < 8; l++) S4[l] = 0.f;
#pragma unroll
            for (int t = 0; t < 16; t++) {
                const float* dr = dch + t * 8;
                float di = dr[i1], dj = dr[j1], dk = dr[k1];
                float ga = l3 + dk * (l2 * 0.5f + dj * (p1 * (1.f/6.f) + di * (1.f/24.f)));
#pragma unroll
                for (int l = 0; l < 8; l++) S4[l] += ga * dr[l];
                l3 += dk * (l2 + dj * (p1 * 0.5f + di * (1.f/6.f)));
                l2 += (p1 + di * 0.5f) * dj;
                p1 += di;
            }
            loc3[row1 * 9 + k1] = l3;
            if (k1 == 0) loc2[row1] = l2;
            if (jk == 0) loc1[i1] = p1;
            __syncthreads();

            float* dst = sSnap0 + c * SIGSZ;
            const float* l3p = &loc3[jk * 9];
            const float* l2p = &loc2[k1 * 8];
            if (c == 0) {
#pragma unroll
                for (int l = 0; l < 8; l++) dst[P4OFF + tid * 9 + l] = S4[l];
                dst[P3OFF + row1 * 9 + k1] = l3;
                if (tid < 64) dst[8 + tid] = loc2[tid];
                if (tid < 8)  dst[tid] = loc1[tid];
            } else {
                const float* prv = sSnap0 + (c - 1) * SIGSZ;
                float a1 = prv[i1], a2 = prv[8 + row1], a3 = prv[P3OFF + row1 * 9 + k1];
#pragma unroll
                for (int l = 0; l < 8; l++) {
                    float v3 = l3p[l], v2 = l2p[l], v1 = loc1[l];
                    dst[P4OFF + tid * 9 + l] = prv[P4OFF + tid * 9 + l] + S4[l]
                                             + a1 * v3 + a2 * v2 + a3 * v1;
                }
                dst[P3OFF + row1 * 9 + k1] = a3 + l3 + a1 * loc2[jk] + a2 * loc1[k1];
                if (tid < 64) dst[8 + tid] = prv[8 + tid] + loc2[tid] + prv[tid >> 3] * loc1[tid & 7];
                if (tid < 8)  dst[tid] = prv[tid] + loc1[tid];
            }
            __syncthreads();
        }

        // group total (snapshot 3) -> T, coalesced write-through
        {
            const float* s3 = sSnap0 + 3 * SIGSZ;
            float* Tr = T + (size_t)bid * MEM;
            for (int m = tid; m < MEM; m += 512) {
                float v;
                if (m < 72) v = s3[m];
                else if (m < 584) { int e = m - 72;  v = s3[P3OFF + (e >> 3) * 9 + (e & 7)]; }
                else              { int e = m - 584; v = s3[P4OFF + (e >> 3) * 9 + (e & 7)]; }
                stc(Tr + m, v);
            }
        }
        __syncthreads();               // all waves' stc stores vmcnt-drained
        if (tid == 0) stu(&fflag[bid], 1u);
    }

    // ================= phase 2: scan (blocks 0..127) ===========================
    if (bid < 128) {
        float* st1 = smem + 21024;             // 32*8
        float* st2 = smem + 21024 + 256;       // 32*64
        float* st3 = smem + 21024 + 2304;      // 32*32
        float* sp1 = smem + 21024 + 3328;      // 32*8
        float* sp2 = smem + 21024 + 3584;      // 32*64
        float* sp3 = smem + 21024 + 5632;      // 32*32
        const int b2 = bid >> 4, s = bid & 15;
        const int bBase = b2 * NG;

        if (tid < 32) waitflag(fflag + bBase + tid);
        __syncthreads();

        const int jkl   = ((s & 1) << 8) | (tid & 255);
        const int m4idx = s * 256 + (tid & 255);

        float rL4[NG], rL3[NG];
        if (tid < 256) {
#pragma unroll
            for (int gg = 0; gg < NG; gg++) {
                const float* Trow = T + (size_t)(bBase + gg) * MEM;
                rL4[gg] = ldc(Trow + 584 + m4idx);
                rL3[gg] = ldc(Trow + 72 + jkl);
            }
        }
        if (tid < 256) {
            int gg = tid >> 3, i = tid & 7;
            st1[gg * 8 + i] = ldc(T + (size_t)(bBase + gg) * MEM + i);
        }
        for (int m = tid; m < NG * 64; m += 512) {
            int gg = m >> 6, e = m & 63;
            st2[gg * 64 + e] = ldc(T + (size_t)(bBase + gg) * MEM + 8 + e);
        }
        for (int m = tid; m < NG * 32; m += 512) {
            int gg = m >> 5, e = m & 31;
            st3[gg * 32 + e] = ldc(T + (size_t)(bBase + gg) * MEM + 72 + s * 32 + e);
        }
        __syncthreads();

        if (tid < 64) {
            int i = tid >> 3, k = tid & 7;
            float p1acc = 0.f, p2acc = 0.f;
            for (int gg = 0; gg < NG; gg++) {
                sp2[gg * 64 + tid] = p2acc;
                if (k == 0) sp1[gg * 8 + i] = p1acc;
                if (s == 0) {
                    float* prow = P + (size_t)(bBase + gg) * MEM;
                    stc(prow + 8 + tid, p2acc);
                    if (k == 0) stc(prow + i, p1acc);
                }
                p2acc += st2[gg * 64 + tid] + p1acc * st1[gg * 8 + k];
                p1acc += st1[gg * 8 + i];
            }
        }
        __syncthreads();
        if (tid < 32) {
            int ijk = s * 32 + tid;
            int i = ijk >> 6, jk2 = ijk & 63, ij = ijk >> 3, k = ijk & 7;
            float acc3 = 0.f;
            for (int gg = 0; gg < NG; gg++) {
                sp3[gg * 32 + tid] = acc3;
                stc(P + (size_t)(bBase + gg) * MEM + 72 + ijk, acc3);
                acc3 += st3[gg * 32 + tid] + sp1[gg * 8 + i] * st2[gg * 64 + jk2]
                      + sp2[gg * 64 + ij] * st1[gg * 8 + k];
            }
        }
        __syncthreads();
        if (tid < 256) {
            const int i  = s >> 1;
            const int ij = (s << 2) + ((tid & 255) >> 6);
            const int kl = tid & 63, l = tid & 7, p3 = (tid & 255) >> 3;
            float acc4 = 0.f;
            size_t prowBase = (size_t)bBase * MEM + 584 + m4idx;
#pragma unroll
            for (int gg = 0; gg < NG; gg++) {
                stc(P + prowBase + (size_t)gg * MEM, acc4);
                acc4 += rL4[gg] + sp1[gg * 8 + i] * rL3[gg]
                      + sp2[gg * 64 + ij] * st2[gg * 64 + kl]
                      + sp3[gg * 32 + p3] * st1[gg * 8 + l];
            }
        }
        __syncthreads();
        if (tid == 0) stu(&sflag[bid], 1u);
    }

    // ================= phase 3: apply own group (all 256 blocks) ===============
    {
        float* sR = smem + 21024;      // 648
        float* sG = smem + 21672;      // 4096
        const float* Prow = P + (size_t)bid * MEM;

        if (tid < 16) waitflag(sflag + b * 16 + tid);
        __syncthreads();

        // coalesced uncached stage of P L4 into LDS, then per-thread gather
        for (int m = tid; m < 4096; m += 512) sG[m] = ldc(Prow + 584 + m);
        const float a1  = ldc(Prow + i1);
        const float a2  = ldc(Prow + 8 + row1);
        const float a3  = ldc(Prow + 72 + tid);        // L3 row of this thread
        const float p2v = (tid < 64) ? ldc(Prow + 8 + tid) : 0.f;
        const float p1v = (tid < 8) ? ldc(Prow + tid) : 0.f;
        const float p2i = (tid < 64) ? ldc(Prow + (tid >> 3)) : 0.f;
        __syncthreads();               // sG ready

        float pP4[8];
#pragma unroll
        for (int l = 0; l < 8; l++) pP4[l] = sG[tid * 8 + l];
        __syncthreads();               // gathers complete; sG reusable later

        float pool4[8];
#pragma unroll
        for (int l = 0; l < 8; l++) pool4[l] = 0.f;
        float pool3 = 0.f, pool2 = 0.f, pool1 = 0.f;

        for (int c = 0; c < 4; ++c) {
            const float* sAc = sSnap0 + c * SIGSZ;
            const float* q3p = &sAc[P3OFF + jk * 9];
            const float* q2p = &sAc[8 + k1 * 8];
            float R4[8];
#pragma unroll
            for (int l = 0; l < 8; l++) {
                float v3 = q3p[l], v2 = q2p[l], v1 = sAc[l];
                R4[l] = pP4[l] + sAc[P4OFF + tid * 9 + l] + a1 * v3 + a2 * v2 + a3 * v1;
            }
            float R3 = a3 + sAc[P3OFF + row1 * 9 + k1] + a1 * sAc[8 + jk] + a2 * sAc[k1];
            float R2v = 0.f, R1v = 0.f;
            if (tid < 64) R2v = p2v + sAc[8 + tid] + p2i * sAc[tid & 7];
            if (tid < 8)  R1v = p1v + sAc[tid];

            sR[P3OFF + row1 * 9 + k1] = R3;
            if (tid < 64) sR[8 + tid] = R2v;
            if (tid < 8)  sR[tid] = R1v;
            __syncthreads();

            float q23 = sR[i1] * sR[8 + jk] + sR[8 + row1] * sR[k1];
            {
                float s1i = sR[i1], s1j = sR[j1], s1k = sR[k1];
                float s2ij = sR[8 + row1];
                float s2jk = sR[8 + jk];
                const float* r3p = &sR[P3OFF + jk * 9];
                const float* r2p = &sR[8 + k1 * 8];
#pragma unroll
                for (int l = 0; l < 8; l++) {
                    float s1l = sR[l];
                    float p22 = s1k * s1l;
                    float q23l = s1j * r2p[l] + s2jk * s1l;
                    float p24 = s1i * r3p[l] + s2ij * r2p[l] + R3 * s1l;
                    float p34 = s1i * q23l + s2ij * p22;
                    float p44 = s1i * s1j * p22;
                    pool4[l] += R4[l] - 0.5f * p24 + (1.f/3.f) * p34 - 0.25f * p44;
                }
                pool3 += R3 - 0.5f * q23 + (1.f/3.f) * s1i * s1j * s1k;
                if (tid < 64) pool2 += R2v - 0.5f * sR[tid >> 3] * sR[tid & 7];
                if (tid < 8)  pool1 += R1v;
            }
            __syncthreads();
        }

        // stage pool4 into sG, then coalesced uncached stores of the partial row
#pragma unroll
        for (int l = 0; l < 8; l++) sG[tid * 8 + l] = pool4[l];
        __syncthreads();
        float* pb = partial + (size_t)bid * MEM;
        for (int m = tid; m < 4096; m += 512) stc(pb + 584 + m, sG[m]);
        stc(pb + 72 + tid, pool3);
        if (tid < 64) stc(pb + 8 + tid, pool2);
        if (tid < 8)  stc(pb + tid, pool1);
        __syncthreads();               // vmcnt drained
        if (tid == 0) stu(&aflag[bid], 1u);
    }

    if (bid >= 147) return;

    // ================= phase 4: gemv (blocks 0..146) ===========================
    {
        float* sp = smem + 21024;      // 8*32
        const int kc = bid;
        const int k0 = kc * 32;

        if (tid < 256) waitflag(aflag + tid);   // all 256 apply rows
        __syncthreads();

        if (tid < 256) {
            int bb = tid >> 5, k = tid & 31;
            float sum = 0.f;
            if (k0 + k < MEM) {
                const float* pp = partial + (size_t)(bb * NG) * MEM + k0 + k;
                for (int gg = 0; gg < NG; gg++) sum += ldc(pp + (size_t)gg * MEM);
            }
            sp[bb * 32 + k] = sum * (1.f / 128.f);
        }
        __syncthreads();
        if (tid < 256) {
            float acc[8];
#pragma unroll
            for (int bb = 0; bb < 8; bb++) acc[bb] = 0.f;
            int kend = (k0 + 32 < MEM) ? 32 : (MEM - k0);
            for (int k = 0; k < kend; k++) {
                float wv = W1[(size_t)(k0 + k) * 256 + tid];
#pragma unroll
                for (int bb = 0; bb < 8; bb++) acc[bb] += sp[bb * 32 + k] * wv;
            }
#pragma unroll
            for (int bb = 0; bb < 8; bb++) stc(hpart + (size_t)kc * 2048 + bb * 256 + tid, acc[bb]);
        }
        __syncthreads();
        if (tid == 0) stu(&gflag[kc], 1u);
    }

    if (bid >= 8) return;

    // ================= phase 5: final (blocks 0..7) ============================
    {
        float* sRed = smem + 21024;
        if (tid < 147) waitflag(gflag + tid);
        __syncthreads();
        if (tid < 256) {
            float v = 0.f;
#pragma unroll 7
            for (int kc = 0; kc < 147; kc++) v += ldc(hpart + (size_t)kc * 2048 + bid * 256 + tid);
            v += b1[tid];
            v = fmaxf(v, 0.f) * W2[tid];
            sRed[tid] = v;
        }
        __syncthreads();
        for (int s = 128; s > 0; s >>= 1) {
            if (tid < s) sRed[tid] += sRed[tid + s];
            __syncthreads();
        }
        if (tid == 0) outp[bid] = sRed[0] + b2[0];
    }
}

// ------------------------------------------------ launch
extern "C" void kernel_launch(void* const* d_in, const int* in_sizes, int n_in,
                              void* d_out, int out_size, void* d_ws, size_t ws_size,
                              hipStream_t stream) {
    const float* x  = (const float*)d_in[0];
    const float* W1 = (const float*)d_in[1];
    const float* b1 = (const float*)d_in[2];
    const float* W2 = (const float*)d_in[3];
    const float* b2 = (const float*)d_in[4];
    float* out = (float*)d_out;

    float* ws = (float*)d_ws;
    float* T       = ws;                            // 256*MEM (group totals)
    float* P       = T + (size_t)256 * MEM;         // 256*MEM (exclusive group prefixes)
    float* partial = P + (size_t)256 * MEM;         // 256*MEM (per-group pooled rows)
    float* hpart   = partial + (size_t)256 * MEM;   // 147*2048 (gemv partials)
    size_t flagoff = (size_t)256 * MEM * 3 + (size_t)147 * 2048;
    flagoff = (flagoff + 31) & ~(size_t)31;
    unsigned* flags = (unsigned*)(ws + flagoff);    // 787 flags

    // workspace is poisoned each iteration: flags MUST be zeroed. Stream-ordered.
    hipMemsetAsync(flags, 0, 4096, stream);
    mega_kernel<<<256, 512, 0, stream>>>(x, W1, b1, W2, b2, out, T, P, partial, hpart, flags);
}

// Round 11
// 129.392 us; speedup vs baseline: 1.0033x; 1.0033x over previous
//
#include <hip/hip_runtime.h>

// BLAMem: truncated tensor-algebra (depth 4, C=8) log-signature memory.
// Round-18: R10 mega-kernel with ONE change: __launch_bounds__(512, 2).
// R10 post-mortem: 512-thread widening cut the kernel 89->70us BUT VGPR dropped
// 176->128 and WRITE/FETCH grew +21/+10MB => the compiler, lacking an occupancy
// target, capped at 128 VGPRs and SPILLED the scan preload (rL4[32]+rL3[32]) and
// apply state to scratch (scratch = HBM traffic, on the critical path). LDS
// (111KB) already pins us at 1 block/CU = 2 waves/SIMD, so a 256-VGPR budget is
// free: launch_bounds(512, 2) declares exactly that. Everything else is
// byte-identical to the R10 kernel (passed, absmax 0.0).
// Structure: fold(256 blk)+scan(128)+apply(256)+gemv(147)+final(8), fence-free
// sc0sc1 flag dataflow, ~40ms poll timeouts, NO atomic RMW, coalesced uncached
// cross-block buffers (~30MB logical).

#define MEM   4680   // 8 + 64 + 512 + 4096 (unpadded global layout)
#define NG    32     // groups per batch
#define TLEN  2048

#define P3OFF 72
#define P4OFF 648
#define SIGSZ 5256

__device__ __forceinline__ float ldc(const float* p) {
    return __hip_atomic_load(p, __ATOMIC_RELAXED, __HIP_MEMORY_SCOPE_SYSTEM);
}
__device__ __forceinline__ void stc(float* p, float v) {
    __hip_atomic_store(p, v, __ATOMIC_RELAXED, __HIP_MEMORY_SCOPE_SYSTEM);
}
__device__ __forceinline__ unsigned ldu(const unsigned* p) {
    return __hip_atomic_load(p, __ATOMIC_RELAXED, __HIP_MEMORY_SCOPE_SYSTEM);
}
__device__ __forceinline__ void stu(unsigned* p, unsigned v) {
    __hip_atomic_store(p, v, __ATOMIC_RELAXED, __HIP_MEMORY_SCOPE_SYSTEM);
}
#define SPIN_TIMEOUT 4000000ull   // ~40ms

__device__ __forceinline__ void waitflag(const unsigned* f) {
    unsigned long long t0 = __builtin_amdgcn_s_memrealtime();
    while (ldu(f) == 0u) {
        __builtin_amdgcn_s_sleep(2);
        if (__builtin_amdgcn_s_memrealtime() - t0 > SPIN_TIMEOUT) break;
    }
}

// smem layout (floats): sSnap [0,21024) persistent through apply.
// Aliased @21024: fold {sInc 512, U 648}; scan {6656}; apply {sR 648, sG 4096};
// gemv {sp 256}; final {sRed 256}. Total 27680 floats = 110.7KB -> 1 block/CU.
#define SMEM_TOTAL 27680

__global__ __launch_bounds__(512, 2) void mega_kernel(
    const float* __restrict__ x,  const float* __restrict__ W1,
    const float* __restrict__ b1, const float* __restrict__ W2,
    const float* __restrict__ b2, float* __restrict__ outp,
    float* __restrict__ T, float* __restrict__ P,
    float* __restrict__ partial, float* __restrict__ hpart,
    unsigned* __restrict__ flags)
{
    const int bid = blockIdx.x;
    const int tid = threadIdx.x;          // 0..511 : one L4 row per thread
    const int b = bid >> 5, g = bid & 31;

    __shared__ __attribute__((aligned(16))) float smem[SMEM_TOTAL];

    unsigned* fflag = flags;          // 256 fold-done
    unsigned* sflag = flags + 256;    // 128 scan-done
    unsigned* aflag = flags + 384;    // 256 apply-done
    unsigned* gflag = flags + 640;    // 147 gemv-done

    float* sSnap0 = smem;             // 4 x SIGSZ

    const int i1 = tid >> 6;          // i   of row (i,j,k)
    const int j1 = (tid >> 3) & 7;    // j
    const int k1 = tid & 7;           // k
    const int row1 = tid >> 3;        // ij in [0,64)
    const int jk = tid & 63;          // jk in [0,64)

    // ================= phase 1: fold (all 256 blocks), snapshots in LDS ========
    {
        float* sInc = smem + 21024;    // 512
        float* U    = smem + 21536;    // 648
        float* loc3 = U;               // 576 (64 rows x 9)
        float* loc2 = U + 576;         // 64
        float* loc1 = U + 640;         // 8

        {   // one element per thread
            int e = tid;
            int s = e >> 3, c = e & 7;
            int t = g * 64 + s;
            float v;
            if (c < 7) {
                float cur  = x[(b * TLEN + t) * 7 + c];
                float prev = (t > 0) ? x[(b * TLEN + t - 1) * 7 + c] : 0.f;
                v = cur - prev;
            } else v = (t > 0) ? (1.f / 2047.f) : 0.f;
            sInc[e] = v;
        }
        __syncthreads();

        for (int c = 0; c < 4; ++c) {
            const float* dch = &sInc[c * 128];
            float p1 = 0.f, l2 = 0.f, l3 = 0.f;
            float S4[8];
#pragma unroll
            for (int l = 0; l < 8; l++) S4[l] = 0.f;
#pragma unroll
            for (int t = 0; t < 16; t++) {
                const float* dr = dch + t * 8;
                float di = dr[i1], dj = dr[j1], dk = dr[k1];
                float ga = l3 + dk * (l2 * 0.5f + dj * (p1 * (1.f/6.f) + di * (1.f/24.f)));
#pragma unroll
                for (int l = 0; l < 8; l++) S4[l] += ga * dr[l];
                l3 += dk * (l2 + dj * (p1 * 0.5f + di * (1.f/6.f)));
                l2 += (p1 + di * 0.5f) * dj;
                p1 += di;
            }
            loc3[row1 * 9 + k1] = l3;
            if (k1 == 0) loc2[row1] = l2;
            if (jk == 0) loc1[i1] = p1;
            __syncthreads();

            float* dst = sSnap0 + c * SIGSZ;
            const float* l3p = &loc3[jk * 9];
            const float* l2p = &loc2[k1 * 8];
            if (c == 0) {
#pragma unroll
                for (int l = 0; l < 8; l++) dst[P4OFF + tid * 9 + l] = S4[l];
                dst[P3OFF + row1 * 9 + k1] = l3;
                if (tid < 64) dst[8 + tid] = loc2[tid];
                if (tid < 8)  dst[tid] = loc1[tid];
            } else {
                const float* prv = sSnap0 + (c - 1) * SIGSZ;
                float a1 = prv[i1], a2 = prv[8 + row1], a3 = prv[P3OFF + row1 * 9 + k1];
#pragma unroll
                for (int l = 0; l < 8; l++) {
                    float v3 = l3p[l], v2 = l2p[l], v1 = loc1[l];
                    dst[P4OFF + tid * 9 + l] = prv[P4OFF + tid * 9 + l] + S4[l]
                                             + a1 * v3 + a2 * v2 + a3 * v1;
                }
                dst[P3OFF + row1 * 9 + k1] = a3 + l3 + a1 * loc2[jk] + a2 * loc1[k1];
                if (tid < 64) dst[8 + tid] = prv[8 + tid] + loc2[tid] + prv[tid >> 3] * loc1[tid & 7];
                if (tid < 8)  dst[tid] = prv[tid] + loc1[tid];
            }
            __syncthreads();
        }

        // group total (snapshot 3) -> T, coalesced write-through
        {
            const float* s3 = sSnap0 + 3 * SIGSZ;
            float* Tr = T + (size_t)bid * MEM;
            for (int m = tid; m < MEM; m += 512) {
                float v;
                if (m < 72) v = s3[m];
                else if (m < 584) { int e = m - 72;  v = s3[P3OFF + (e >> 3) * 9 + (e & 7)]; }
                else              { int e = m - 584; v = s3[P4OFF + (e >> 3) * 9 + (e & 7)]; }
                stc(Tr + m, v);
            }
        }
        __syncthreads();               // all waves' stc stores vmcnt-drained
        if (tid == 0) stu(&fflag[bid], 1u);
    }

    // ================= phase 2: scan (blocks 0..127) ===========================
    if (bid < 128) {
        float* st1 = smem + 21024;             // 32*8
        float* st2 = smem + 21024 + 256;       // 32*64
        float* st3 = smem + 21024 + 2304;      // 32*32
        float* sp1 = smem + 21024 + 3328;      // 32*8
        float* sp2 = smem + 21024 + 3584;      // 32*64
        float* sp3 = smem + 21024 + 5632;      // 32*32
        const int b2 = bid >> 4, s = bid & 15;
        const int bBase = b2 * NG;

        if (tid < 32) waitflag(fflag + bBase + tid);
        __syncthreads();

        const int jkl   = ((s & 1) << 8) | (tid & 255);
        const int m4idx = s * 256 + (tid & 255);

        float rL4[NG], rL3[NG];
        if (tid < 256) {
#pragma unroll
            for (int gg = 0; gg < NG; gg++) {
                const float* Trow = T + (size_t)(bBase + gg) * MEM;
                rL4[gg] = ldc(Trow + 584 + m4idx);
                rL3[gg] = ldc(Trow + 72 + jkl);
            }
        }
        if (tid < 256) {
            int gg = tid >> 3, i = tid & 7;
            st1[gg * 8 + i] = ldc(T + (size_t)(bBase + gg) * MEM + i);
        }
        for (int m = tid; m < NG * 64; m += 512) {
            int gg = m >> 6, e = m & 63;
            st2[gg * 64 + e] = ldc(T + (size_t)(bBase + gg) * MEM + 8 + e);
        }
        for (int m = tid; m < NG * 32; m += 512) {
            int gg = m >> 5, e = m & 31;
            st3[gg * 32 + e] = ldc(T + (size_t)(bBase + gg) * MEM + 72 + s * 32 + e);
        }
        __syncthreads();

        if (tid < 64) {
            int i = tid >> 3, k = tid & 7;
            float p1acc = 0.f, p2acc = 0.f;
            for (int gg = 0; gg < NG; gg++) {
                sp2[gg * 64 + tid] = p2acc;
                if (k == 0) sp1[gg * 8 + i] = p1acc;
                if (s == 0) {
                    float* prow = P + (size_t)(bBase + gg) * MEM;
                    stc(prow + 8 + tid, p2acc);
                    if (k == 0) stc(prow + i, p1acc);
                }
                p2acc += st2[gg * 64 + tid] + p1acc * st1[gg * 8 + k];
                p1acc += st1[gg * 8 + i];
            }
        }
        __syncthreads();
        if (tid < 32) {
            int ijk = s * 32 + tid;
            int i = ijk >> 6, jk2 = ijk & 63, ij = ijk >> 3, k = ijk & 7;
            float acc3 = 0.f;
            for (int gg = 0; gg < NG; gg++) {
                sp3[gg * 32 + tid] = acc3;
                stc(P + (size_t)(bBase + gg) * MEM + 72 + ijk, acc3);
                acc3 += st3[gg * 32 + tid] + sp1[gg * 8 + i] * st2[gg * 64 + jk2]
                      + sp2[gg * 64 + ij] * st1[gg * 8 + k];
            }
        }
        __syncthreads();
        if (tid < 256) {
            const int i  = s >> 1;
            const int ij = (s << 2) + ((tid & 255) >> 6);
            const int kl = tid & 63, l = tid & 7, p3 = (tid & 255) >> 3;
            float acc4 = 0.f;
            size_t prowBase = (size_t)bBase * MEM + 584 + m4idx;
#pragma unroll
            for (int gg = 0; gg < NG; gg++) {
                stc(P + prowBase + (size_t)gg * MEM, acc4);
                acc4 += rL4[gg] + sp1[gg * 8 + i] * rL3[gg]
                      + sp2[gg * 64 + ij] * st2[gg * 64 + kl]
                      + sp3[gg * 32 + p3] * st1[gg * 8 + l];
            }
        }
        __syncthreads();
        if (tid == 0) stu(&sflag[bid], 1u);
    }

    // ================= phase 3: apply own group (all 256 blocks) ===============
    {
        float* sR = smem + 21024;      // 648
        float* sG = smem + 21672;      // 4096
        const float* Prow = P + (size_t)bid * MEM;

        if (tid < 16) waitflag(sflag + b * 16 + tid);
        __syncthreads();

        // coalesced uncached stage of P L4 into LDS, then per-thread gather
        for (int m = tid; m < 4096; m += 512) sG[m] = ldc(Prow + 584 + m);
        const float a1  = ldc(Prow + i1);
        const float a2  = ldc(Prow + 8 + row1);
        const float a3  = ldc(Prow + 72 + tid);        // L3 row of this thread
        const float p2v = (tid < 64) ? ldc(Prow + 8 + tid) : 0.f;
        const float p1v = (tid < 8) ? ldc(Prow + tid) : 0.f;
        const float p2i = (tid < 64) ? ldc(Prow + (tid >> 3)) : 0.f;
        __syncthreads();               // sG ready

        float pP4[8];
#pragma unroll
        for (int l = 0; l < 8; l++) pP4[l] = sG[tid * 8 + l];
        __syncthreads();               // gathers complete; sG reusable later

        float pool4[8];
#pragma unroll
        for (int l = 0; l < 8; l++) pool4[l] = 0.f;
        float pool3 = 0.f, pool2 = 0.f, pool1 = 0.f;

        for (int c = 0; c < 4; ++c) {
            const float* sAc = sSnap0 + c * SIGSZ;
            const float* q3p = &sAc[P3OFF + jk * 9];
            const float* q2p = &sAc[8 + k1 * 8];
            float R4[8];
#pragma unroll
            for (int l = 0; l < 8; l++) {
                float v3 = q3p[l], v2 = q2p[l], v1 = sAc[l];
                R4[l] = pP4[l] + sAc[P4OFF + tid * 9 + l] + a1 * v3 + a2 * v2 + a3 * v1;
            }
            float R3 = a3 + sAc[P3OFF + row1 * 9 + k1] + a1 * sAc[8 + jk] + a2 * sAc[k1];
            float R2v = 0.f, R1v = 0.f;
            if (tid < 64) R2v = p2v + sAc[8 + tid] + p2i * sAc[tid & 7];
            if (tid < 8)  R1v = p1v + sAc[tid];

            sR[P3OFF + row1 * 9 + k1] = R3;
            if (tid < 64) sR[8 + tid] = R2v;
            if (tid < 8)  sR[tid] = R1v;
            __syncthreads();

            float q23 = sR[i1] * sR[8 + jk] + sR[8 + row1] * sR[k1];
            {
                float s1i = sR[i1], s1j = sR[j1], s1k = sR[k1];
                float s2ij = sR[8 + row1];
                float s2jk = sR[8 + jk];
                const float* r3p = &sR[P3OFF + jk * 9];
                const float* r2p = &sR[8 + k1 * 8];
#pragma unroll
                for (int l = 0; l < 8; l++) {
                    float s1l = sR[l];
                    float p22 = s1k * s1l;
                    float q23l = s1j * r2p[l] + s2jk * s1l;
                    float p24 = s1i * r3p[l] + s2ij * r2p[l] + R3 * s1l;
                    float p34 = s1i * q23l + s2ij * p22;
                    float p44 = s1i * s1j * p22;
                    pool4[l] += R4[l] - 0.5f * p24 + (1.f/3.f) * p34 - 0.25f * p44;
                }
                pool3 += R3 - 0.5f * q23 + (1.f/3.f) * s1i * s1j * s1k;
                if (tid < 64) pool2 += R2v - 0.5f * sR[tid >> 3] * sR[tid & 7];
                if (tid < 8)  pool1 += R1v;
            }
            __syncthreads();
        }

        // stage pool4 into sG, then coalesced uncached stores of the partial row
#pragma unroll
        for (int l = 0; l < 8; l++) sG[tid * 8 + l] = pool4[l];
        __syncthreads();
        float* pb = partial + (size_t)bid * MEM;
        for (int m = tid; m < 4096; m += 512) stc(pb + 584 + m, sG[m]);
        stc(pb + 72 + tid, pool3);
        if (tid < 64) stc(pb + 8 + tid, pool2);
        if (tid < 8)  stc(pb + tid, pool1);
        __syncthreads();               // vmcnt drained
        if (tid == 0) stu(&aflag[bid], 1u);
    }

    if (bid >= 147) return;

    // ================= phase 4: gemv (blocks 0..146) ===========================
    {
        float* sp = smem + 21024;      // 8*32
        const int kc = bid;
        const int k0 = kc * 32;

        if (tid < 256) waitflag(aflag + tid);   // all 256 apply rows
        __syncthreads();

        if (tid < 256) {
            int bb = tid >> 5, k = tid & 31;
            float sum = 0.f;
            if (k0 + k < MEM) {
                const float* pp = partial + (size_t)(bb * NG) * MEM + k0 + k;
                for (int gg = 0; gg < NG; gg++) sum += ldc(pp + (size_t)gg * MEM);
            }
            sp[bb * 32 + k] = sum * (1.f / 128.f);
        }
        __syncthreads();
        if (tid < 256) {
            float acc[8];
#pragma unroll
            for (int bb = 0; bb < 8; bb++) acc[bb] = 0.f;
            int kend = (k0 + 32 < MEM) ? 32 : (MEM - k0);
            for (int k = 0; k < kend; k++) {
                float wv = W1[(size_t)(k0 + k) * 256 + tid];
#pragma unroll
                for (int bb = 0; bb < 8; bb++) acc[bb] += sp[bb * 32 + k] * wv;
            }
#pragma unroll
            for (int bb = 0; bb < 8; bb++) stc(hpart + (size_t)kc * 2048 + bb * 256 + tid, acc[bb]);
        }
        __syncthreads();
        if (tid == 0) stu(&gflag[kc], 1u);
    }

    if (bid >= 8) return;

    // ================= phase 5: final (blocks 0..7) ============================
    {
        float* sRed = smem + 21024;
        if (tid < 147) waitflag(gflag + tid);
        __syncthreads();
        if (tid < 256) {
            float v = 0.f;
#pragma unroll 7
            for (int kc = 0; kc < 147; kc++) v += ldc(hpart + (size_t)kc * 2048 + bid * 256 + tid);
            v += b1[tid];
            v = fmaxf(v, 0.f) * W2[tid];
            sRed[tid] = v;
        }
        __syncthreads();
        for (int s = 128; s > 0; s >>= 1) {
            if (tid < s) sRed[tid] += sRed[tid + s];
            __syncthreads();
        }
        if (tid == 0) outp[bid] = sRed[0] + b2[0];
    }
}

// ------------------------------------------------ launch
extern "C" void kernel_launch(void* const* d_in, const int* in_sizes, int n_in,
                              void* d_out, int out_size, void* d_ws, size_t ws_size,
                              hipStream_t stream) {
    const float* x  = (const float*)d_in[0];
    const float* W1 = (const float*)d_in[1];
    const float* b1 = (const float*)d_in[2];
    const float* W2 = (const float*)d_in[3];
    const float* b2 = (const float*)d_in[4];
    float* out = (float*)d_out;

    float* ws = (float*)d_ws;
    float* T       = ws;                            // 256*MEM (group totals)
    float* P       = T + (size_t)256 * MEM;         // 256*MEM (exclusive group prefixes)
    float* partial = P + (size_t)256 * MEM;         // 256*MEM (per-group pooled rows)
    float* hpart   = partial + (size_t)256 * MEM;   // 147*2048 (gemv partials)
    size_t flagoff = (size_t)256 * MEM * 3 + (size_t)147 * 2048;
    flagoff = (flagoff + 31) & ~(size_t)31;
    unsigned* flags = (unsigned*)(ws + flagoff);    // 787 flags

    // workspace is poisoned each iteration: flags MUST be zeroed. Stream-ordered.
    hipMemsetAsync(flags, 0, 4096, stream);
    mega_kernel<<<256, 512, 0, stream>>>(x, W1, b1, W2, b2, out, T, P, partial, hpart, flags);
}